// Round 6
// baseline (135.680 us; speedup 1.0000x reference)
//
#include <hip/hip_runtime.h>
#include <stdint.h>

typedef unsigned long long u64;

#define NPTS 32768
#define NCEN 512
#define DIM  128
#define TOPK 10

#define KSTEP 32
#define LDX 132            // xT padded row (floats)
#define LDC 516            // cT padded row (floats)
#define KPAD 81            // keys row pad (u64) to break bank alignment

// smem: GEMM phase = (32*132 + 32*516)*4 = 82944 B
//       topk phase = 128*81*8 (keys) + 128*10*4 (merged idx) = 88064 B
#define SMEM_BYTES 88064

// ---------------- numpy pairwise_sum(v*v) over n=128, bit-exact ----------------
// numpy (n <= PW_BLOCKSIZE=128): 8 chains r_j = sum_b fl(a[8b+j]^2), b ascending,
// then ((r0+r1)+(r2+r3))+((r4+r5)+(r6+r7)). Products rounded separately (no FMA).
__global__ __launch_bounds__(256) void np_rownorm(const float* __restrict__ src,
                                                  float* __restrict__ dst, int nrows) {
  const int t = threadIdx.x;
  const int lane = t & 63;
  const int wv = t >> 6;
  const int g = lane >> 3;
  const int j = lane & 7;
  const int row = blockIdx.x * 32 + wv * 8 + g;
  if (row >= nrows) return;
  const float* p = src + (size_t)row * DIM;

  float v = p[j];
  float r = __fmul_rn(v, v);
#pragma unroll
  for (int b = 1; b < 16; ++b) {
    v = p[8 * b + j];
    r = __fadd_rn(r, __fmul_rn(v, v));
  }
  r = __fadd_rn(r, __shfl_xor(r, 1, 64));
  r = __fadd_rn(r, __shfl_xor(r, 2, 64));
  r = __fadd_rn(r, __shfl_xor(r, 4, 64));
  if (j == 0) dst[row] = r;
}

// ---------------- fused: dist GEMM (numpy-exact) + top-10 + gather ----------------
// 1024 threads = 16 waves (2 x 8), block tile 128 points x 512 centers (ALL centers).
// launch_bounds(1024) with NO second arg: 1024-thr block => 4 waves/EU resident
// => compiler must cap VGPR at 128 (round-5's (1024,4) was read as 8 waves/EU
// => 64-VGPR cap => acc spilled to scratch; VGPR_Count=60 confirmed).
__global__ __launch_bounds__(1024) void fused_kernel(const float* __restrict__ x,
                                                     const float* __restrict__ cen,
                                                     const float* __restrict__ x2,
                                                     const float* __restrict__ c2,
                                                     float* __restrict__ out) {
  __shared__ __align__(16) char smem[SMEM_BYTES];
  float* xT = (float*)smem;                              // [KSTEP][LDX]  (k-major, transposed)
  float* cT = (float*)(smem + (size_t)KSTEP * LDX * 4);  // [KSTEP][LDC]
  u64*  keysL   = (u64*)smem;                            // [128][KPAD] : slot wc*10+tt
  unsigned* mergedL = (unsigned*)(smem + (size_t)128 * KPAD * 8);  // [128][10]

  const int t  = threadIdx.x;
  const int pb = blockIdx.x * 128;

  const int wid  = t >> 6;
  const int lane = t & 63;
  const int wr = wid >> 3, wc = wid & 7;   // wave grid 2 (rows) x 8 (cols)
  const int r = lane & 7, c = lane >> 3;
  const int px = wr * 64 + 4 * r;          // local point base (and +32)
  const int cx = wc * 64 + 4 * c;          // global center col base (and +32)

  float acc[8][8];
#pragma unroll
  for (int i = 0; i < 8; ++i)
#pragma unroll
    for (int j = 0; j < 8; ++j) acc[i][j] = 0.f;

  const int xrow = t & 127, xkh = ((t >> 7) & 1) * 16;  // x staging task (threads < 256)
  const int crow = t & 511, ckh = (t >> 9) * 16;        // cen staging task (all threads)

  for (int s = 0; s < DIM / KSTEP; ++s) {
    if (s) __syncthreads();
    if (t < 256) {
      const float4* srcx = (const float4*)&x[(size_t)(pb + xrow) * DIM + s * KSTEP + xkh];
#pragma unroll
      for (int i = 0; i < 4; ++i) {
        float4 v = srcx[i];
        int k = xkh + i * 4;
        xT[(k + 0) * LDX + xrow] = v.x; xT[(k + 1) * LDX + xrow] = v.y;
        xT[(k + 2) * LDX + xrow] = v.z; xT[(k + 3) * LDX + xrow] = v.w;
      }
    }
    {
      const float4* srcc = (const float4*)&cen[(size_t)crow * DIM + s * KSTEP + ckh];
#pragma unroll
      for (int i = 0; i < 4; ++i) {
        float4 v = srcc[i];
        int k = ckh + i * 4;
        cT[(k + 0) * LDC + crow] = v.x; cT[(k + 1) * LDC + crow] = v.y;
        cT[(k + 2) * LDC + crow] = v.z; cT[(k + 3) * LDC + crow] = v.w;
      }
    }
    __syncthreads();

#pragma unroll 4
    for (int kk = 0; kk < KSTEP; ++kk) {
      float4 xa  = *(const float4*)&xT[kk * LDX + px];
      float4 xb  = *(const float4*)&xT[kk * LDX + px + 32];
      float4 ca  = *(const float4*)&cT[kk * LDC + cx];
      float4 cb2 = *(const float4*)&cT[kk * LDC + cx + 32];
      float xv[8] = {xa.x, xa.y, xa.z, xa.w, xb.x, xb.y, xb.z, xb.w};
      float cv[8] = {ca.x, ca.y, ca.z, ca.w, cb2.x, cb2.y, cb2.z, cb2.w};
#pragma unroll
      for (int i = 0; i < 8; ++i)
#pragma unroll
        for (int j = 0; j < 8; ++j)
          acc[i][j] = __fmaf_rn(xv[i], cv[j], acc[i][j]);
    }
  }
  __syncthreads();   // all waves done with xT/cT before keysL overwrites them

  // ---- per-wave-slice selection: sorted top-10 of 64 cols per point ----
  const float4 cc0 = *(const float4*)&c2[cx];
  const float4 cc1 = *(const float4*)&c2[cx + 32];
#pragma unroll
  for (int i = 0; i < 8; ++i) {
    const int pt = px + (i & 3) + (i >> 2) * 32;   // local point row (incl. wr*64)
    const float xx = x2[pb + pt];
    u64 key[8];
#pragma unroll
    for (int jq = 0; jq < 2; ++jq) {
      const float4 cc = jq ? cc1 : cc0;
      float t0 = __fmaf_rn(-2.f, acc[i][jq * 4 + 0], xx);
      float t1 = __fmaf_rn(-2.f, acc[i][jq * 4 + 1], xx);
      float t2 = __fmaf_rn(-2.f, acc[i][jq * 4 + 2], xx);
      float t3 = __fmaf_rn(-2.f, acc[i][jq * 4 + 3], xx);
      float d0 = sqrtf(fmaxf(__fadd_rn(t0, cc.x), 0.f));
      float d1 = sqrtf(fmaxf(__fadd_rn(t1, cc.y), 0.f));
      float d2 = sqrtf(fmaxf(__fadd_rn(t2, cc.z), 0.f));
      float d3 = sqrtf(fmaxf(__fadd_rn(t3, cc.w), 0.f));
      const unsigned cbase = (unsigned)(cx + 32 * jq);
      key[jq * 4 + 0] = ((u64)__float_as_uint(d0) << 32) | (cbase + 0);
      key[jq * 4 + 1] = ((u64)__float_as_uint(d1) << 32) | (cbase + 1);
      key[jq * 4 + 2] = ((u64)__float_as_uint(d2) << 32) | (cbase + 2);
      key[jq * 4 + 3] = ((u64)__float_as_uint(d3) << 32) | (cbase + 3);
    }
#pragma unroll
    for (int tt = 0; tt < TOPK; ++tt) {
      u64 m = key[0];
#pragma unroll
      for (int s2 = 1; s2 < 8; ++s2) m = (key[s2] < m) ? key[s2] : m;
      u64 o;
      o = __shfl_xor(m, 8, 64);  m = (o < m) ? o : m;
      o = __shfl_xor(m, 16, 64); m = (o < m) ? o : m;
      o = __shfl_xor(m, 32, 64); m = (o < m) ? o : m;
      if (c == 0) keysL[(size_t)pt * KPAD + wc * 10 + tt] = m;
#pragma unroll
      for (int s2 = 0; s2 < 8; ++s2)
        if (key[s2] == m) key[s2] = ~0ull;
    }
  }
  __syncthreads();

  // ---- 8-way tournament merge of sorted lists: wave wid owns points wid*8..+7 ----
  {
    const int g  = lane >> 3;
    const int cs = lane & 7;
    const int mp = wid * 8 + g;
    int ptr = 0;
#pragma unroll
    for (int tt = 0; tt < TOPK; ++tt) {
      u64 head = (ptr < 10) ? keysL[(size_t)mp * KPAD + cs * 10 + ptr] : ~0ull;
      u64 m = head;
      u64 o;
      o = __shfl_xor(m, 1, 64); m = (o < m) ? o : m;
      o = __shfl_xor(m, 2, 64); m = (o < m) ? o : m;
      o = __shfl_xor(m, 4, 64); m = (o < m) ? o : m;
      if (head == m) ptr++;                      // unique keys -> exactly one winner
      if (cs == 0) mergedL[mp * 10 + tt] = (unsigned)(m & 0x1ffu);
    }
  }
  __syncthreads();

  // ---- gather + write: 1280 rows per block, 80 per wave, float2/lane ----
  {
    const int p0 = wid * 8;
#pragma unroll
    for (int pp = 0; pp < 8; ++pp) {
#pragma unroll
      for (int tt = 0; tt < TOPK; ++tt) {
        const int idx = mergedL[(p0 + pp) * 10 + tt];
        const float2 v = *(const float2*)&x[(size_t)idx * DIM + 2 * lane];
        *(float2*)&out[(((size_t)(pb + p0 + pp)) * TOPK + tt) * DIM + 2 * lane] = v;
      }
    }
  }
}

extern "C" void kernel_launch(void* const* d_in, const int* in_sizes, int n_in,
                              void* d_out, int out_size, void* d_ws, size_t ws_size,
                              hipStream_t stream) {
  const float* x   = (const float*)d_in[0];
  const float* cen = (const float*)d_in[1];
  float* out = (float*)d_out;

  // ws layout: [c2: 2KB pad->4KB][x2: 128KB]
  float* c2 = (float*)d_ws;
  float* x2 = (float*)((char*)d_ws + 4096);

  np_rownorm<<<NCEN / 32, 256, 0, stream>>>(cen, c2, NCEN);
  np_rownorm<<<NPTS / 32, 256, 0, stream>>>(x, x2, NPTS);
  fused_kernel<<<NPTS / 128, 1024, 0, stream>>>(x, cen, x2, c2, out);
}

// Round 7
// 135.667 us; speedup vs baseline: 1.0001x; 1.0001x over previous
//
#include <hip/hip_runtime.h>
#include <stdint.h>

typedef unsigned long long u64;

#define NPTS 32768
#define NCEN 512
#define DIM  128
#define TOPK 10

#define KSTEP 32
#define LDX 132            // xT padded row (floats)
#define LDC 516            // cT padded row (floats)
#define KPAD 81            // keys row pad (u64) to break bank alignment

// smem: GEMM phase = (32*132 + 32*516)*4 = 82944 B
//       topk phase = 128*81*8 (keys) + 128*10*4 (merged idx) = 88064 B
#define SMEM_BYTES 88064

// ---------------- numpy pairwise_sum(v*v) over n=128, bit-exact ----------------
// numpy (n <= PW_BLOCKSIZE=128): 8 chains r_j = sum_b fl(a[8b+j]^2), b ascending,
// then ((r0+r1)+(r2+r3))+((r4+r5)+(r6+r7)). Products rounded separately (no FMA).
__global__ __launch_bounds__(256) void np_rownorm(const float* __restrict__ src,
                                                  float* __restrict__ dst, int nrows) {
  const int t = threadIdx.x;
  const int lane = t & 63;
  const int wv = t >> 6;
  const int g = lane >> 3;
  const int j = lane & 7;
  const int row = blockIdx.x * 32 + wv * 8 + g;
  if (row >= nrows) return;
  const float* p = src + (size_t)row * DIM;

  float v = p[j];
  float r = __fmul_rn(v, v);
#pragma unroll
  for (int b = 1; b < 16; ++b) {
    v = p[8 * b + j];
    r = __fadd_rn(r, __fmul_rn(v, v));
  }
  r = __fadd_rn(r, __shfl_xor(r, 1, 64));
  r = __fadd_rn(r, __shfl_xor(r, 2, 64));
  r = __fadd_rn(r, __shfl_xor(r, 4, 64));
  if (j == 0) dst[row] = r;
}

// ---------------- fused: dist GEMM (numpy-exact) + top-10 + gather ----------------
// 1024 threads = 16 waves (2 x 8), block tile 128 points x 512 centers (ALL centers).
// LDS=88KB => 1 block/CU => exactly 4 waves/EU. Pin amdgpu_waves_per_eu(4,4) so the
// register allocator targets 4 waves/EU (cap 128 VGPR) instead of its default 8/EU
// (cap 64) which bounced acc[8][8] through AGPRs (rounds 5-6: VGPR_Count=60, 3x
// VALU per FMA, 140us).
__global__ __launch_bounds__(1024)
__attribute__((amdgpu_waves_per_eu(4, 4)))
void fused_kernel(const float* __restrict__ x,
                  const float* __restrict__ cen,
                  const float* __restrict__ x2,
                  const float* __restrict__ c2,
                  float* __restrict__ out) {
  __shared__ __align__(16) char smem[SMEM_BYTES];
  float* xT = (float*)smem;                              // [KSTEP][LDX]  (k-major, transposed)
  float* cT = (float*)(smem + (size_t)KSTEP * LDX * 4);  // [KSTEP][LDC]
  u64*  keysL   = (u64*)smem;                            // [128][KPAD] : slot wc*10+tt
  unsigned* mergedL = (unsigned*)(smem + (size_t)128 * KPAD * 8);  // [128][10]

  const int t  = threadIdx.x;
  const int pb = blockIdx.x * 128;

  const int wid  = t >> 6;
  const int lane = t & 63;
  const int wr = wid >> 3, wc = wid & 7;   // wave grid 2 (rows) x 8 (cols)
  const int r = lane & 7, c = lane >> 3;
  const int px = wr * 64 + 4 * r;          // local point base (and +32)
  const int cx = wc * 64 + 4 * c;          // global center col base (and +32)

  float acc[8][8];
#pragma unroll
  for (int i = 0; i < 8; ++i)
#pragma unroll
    for (int j = 0; j < 8; ++j) acc[i][j] = 0.f;

  const int xrow = t & 127, xkh = ((t >> 7) & 1) * 16;  // x staging task (threads < 256)
  const int crow = t & 511, ckh = (t >> 9) * 16;        // cen staging task (all threads)

  for (int s = 0; s < DIM / KSTEP; ++s) {
    if (s) __syncthreads();
    if (t < 256) {
      const float4* srcx = (const float4*)&x[(size_t)(pb + xrow) * DIM + s * KSTEP + xkh];
#pragma unroll
      for (int i = 0; i < 4; ++i) {
        float4 v = srcx[i];
        int k = xkh + i * 4;
        xT[(k + 0) * LDX + xrow] = v.x; xT[(k + 1) * LDX + xrow] = v.y;
        xT[(k + 2) * LDX + xrow] = v.z; xT[(k + 3) * LDX + xrow] = v.w;
      }
    }
    {
      const float4* srcc = (const float4*)&cen[(size_t)crow * DIM + s * KSTEP + ckh];
#pragma unroll
      for (int i = 0; i < 4; ++i) {
        float4 v = srcc[i];
        int k = ckh + i * 4;
        cT[(k + 0) * LDC + crow] = v.x; cT[(k + 1) * LDC + crow] = v.y;
        cT[(k + 2) * LDC + crow] = v.z; cT[(k + 3) * LDC + crow] = v.w;
      }
    }
    __syncthreads();

#pragma unroll 4
    for (int kk = 0; kk < KSTEP; ++kk) {
      float4 xa  = *(const float4*)&xT[kk * LDX + px];
      float4 xb  = *(const float4*)&xT[kk * LDX + px + 32];
      float4 ca  = *(const float4*)&cT[kk * LDC + cx];
      float4 cb2 = *(const float4*)&cT[kk * LDC + cx + 32];
      float xv[8] = {xa.x, xa.y, xa.z, xa.w, xb.x, xb.y, xb.z, xb.w};
      float cv[8] = {ca.x, ca.y, ca.z, ca.w, cb2.x, cb2.y, cb2.z, cb2.w};
#pragma unroll
      for (int i = 0; i < 8; ++i)
#pragma unroll
        for (int j = 0; j < 8; ++j)
          acc[i][j] = __fmaf_rn(xv[i], cv[j], acc[i][j]);
    }
  }
  __syncthreads();   // all waves done with xT/cT before keysL overwrites them

  // ---- per-wave-slice selection: sorted top-10 of 64 cols per point ----
  const float4 cc0 = *(const float4*)&c2[cx];
  const float4 cc1 = *(const float4*)&c2[cx + 32];
#pragma unroll
  for (int i = 0; i < 8; ++i) {
    const int pt = px + (i & 3) + (i >> 2) * 32;   // local point row (incl. wr*64)
    const float xx = x2[pb + pt];
    u64 key[8];
#pragma unroll
    for (int jq = 0; jq < 2; ++jq) {
      const float4 cc = jq ? cc1 : cc0;
      float t0 = __fmaf_rn(-2.f, acc[i][jq * 4 + 0], xx);
      float t1 = __fmaf_rn(-2.f, acc[i][jq * 4 + 1], xx);
      float t2 = __fmaf_rn(-2.f, acc[i][jq * 4 + 2], xx);
      float t3 = __fmaf_rn(-2.f, acc[i][jq * 4 + 3], xx);
      float d0 = sqrtf(fmaxf(__fadd_rn(t0, cc.x), 0.f));
      float d1 = sqrtf(fmaxf(__fadd_rn(t1, cc.y), 0.f));
      float d2 = sqrtf(fmaxf(__fadd_rn(t2, cc.z), 0.f));
      float d3 = sqrtf(fmaxf(__fadd_rn(t3, cc.w), 0.f));
      const unsigned cbase = (unsigned)(cx + 32 * jq);
      key[jq * 4 + 0] = ((u64)__float_as_uint(d0) << 32) | (cbase + 0);
      key[jq * 4 + 1] = ((u64)__float_as_uint(d1) << 32) | (cbase + 1);
      key[jq * 4 + 2] = ((u64)__float_as_uint(d2) << 32) | (cbase + 2);
      key[jq * 4 + 3] = ((u64)__float_as_uint(d3) << 32) | (cbase + 3);
    }
#pragma unroll
    for (int tt = 0; tt < TOPK; ++tt) {
      u64 m = key[0];
#pragma unroll
      for (int s2 = 1; s2 < 8; ++s2) m = (key[s2] < m) ? key[s2] : m;
      u64 o;
      o = __shfl_xor(m, 8, 64);  m = (o < m) ? o : m;
      o = __shfl_xor(m, 16, 64); m = (o < m) ? o : m;
      o = __shfl_xor(m, 32, 64); m = (o < m) ? o : m;
      if (c == 0) keysL[(size_t)pt * KPAD + wc * 10 + tt] = m;
#pragma unroll
      for (int s2 = 0; s2 < 8; ++s2)
        if (key[s2] == m) key[s2] = ~0ull;
    }
  }
  __syncthreads();

  // ---- 8-way tournament merge of sorted lists: wave wid owns points wid*8..+7 ----
  {
    const int g  = lane >> 3;
    const int cs = lane & 7;
    const int mp = wid * 8 + g;
    int ptr = 0;
#pragma unroll
    for (int tt = 0; tt < TOPK; ++tt) {
      u64 head = (ptr < 10) ? keysL[(size_t)mp * KPAD + cs * 10 + ptr] : ~0ull;
      u64 m = head;
      u64 o;
      o = __shfl_xor(m, 1, 64); m = (o < m) ? o : m;
      o = __shfl_xor(m, 2, 64); m = (o < m) ? o : m;
      o = __shfl_xor(m, 4, 64); m = (o < m) ? o : m;
      if (head == m) ptr++;                      // unique keys -> exactly one winner
      if (cs == 0) mergedL[mp * 10 + tt] = (unsigned)(m & 0x1ffu);
    }
  }
  __syncthreads();

  // ---- gather + write: 1280 rows per block, 80 per wave, float2/lane ----
  {
    const int p0 = wid * 8;
#pragma unroll
    for (int pp = 0; pp < 8; ++pp) {
#pragma unroll
      for (int tt = 0; tt < TOPK; ++tt) {
        const int idx = mergedL[(p0 + pp) * 10 + tt];
        const float2 v = *(const float2*)&x[(size_t)idx * DIM + 2 * lane];
        *(float2*)&out[(((size_t)(pb + p0 + pp)) * TOPK + tt) * DIM + 2 * lane] = v;
      }
    }
  }
}

extern "C" void kernel_launch(void* const* d_in, const int* in_sizes, int n_in,
                              void* d_out, int out_size, void* d_ws, size_t ws_size,
                              hipStream_t stream) {
  const float* x   = (const float*)d_in[0];
  const float* cen = (const float*)d_in[1];
  float* out = (float*)d_out;

  // ws layout: [c2: 2KB pad->4KB][x2: 128KB]
  float* c2 = (float*)d_ws;
  float* x2 = (float*)((char*)d_ws + 4096);

  np_rownorm<<<NCEN / 32, 256, 0, stream>>>(cen, c2, NCEN);
  np_rownorm<<<NPTS / 32, 256, 0, stream>>>(x, x2, NPTS);
  fused_kernel<<<NPTS / 128, 1024, 0, stream>>>(x, cen, x2, c2, out);
}